// Round 3
// baseline (2235.415 us; speedup 1.0000x reference)
//
#include <hip/hip_runtime.h>
#include <hip/hip_bf16.h>
#include <cstdint>
#include <cstddef>

typedef unsigned short ushort_t;
typedef __attribute__((ext_vector_type(8))) __bf16 bf16x8;
typedef __attribute__((ext_vector_type(4))) float f32x4;
typedef __attribute__((ext_vector_type(4))) unsigned int u32x4;
typedef __attribute__((ext_vector_type(2))) unsigned int u32x2;

#define LOG2E 1.44269504088896f

__device__ __forceinline__ float bf2f(unsigned short u) {
  union { unsigned int i; float f; } w; w.i = ((unsigned int)u) << 16; return w.f;
}
__device__ __forceinline__ unsigned short f2bf(float f) {
  union { float f; unsigned int i; } w; w.f = f;
  unsigned int u = w.i;
  u += 0x7fffu + ((u >> 16) & 1);   // RNE
  return (unsigned short)(u >> 16);
}
__device__ __forceinline__ void gld_lds16(const void* g, void* l) {
  __builtin_amdgcn_global_load_lds(
      (const __attribute__((address_space(1))) unsigned int*)g,
      (__attribute__((address_space(3))) unsigned int*)l, 16, 0, 0);
}

// ---------------------------------------------------------------------------
// f32 -> bf16 weight conversion, 4 elems/thread.
// ---------------------------------------------------------------------------
__global__ __launch_bounds__(256)
void cvt_bf16(const float* __restrict__ in, ushort_t* __restrict__ outp, int n) {
  const int i = (blockIdx.x * 256 + threadIdx.x) * 4;
  if (i >= n) return;
  const float4 d = *(const float4*)(in + i);
  u32x2 o;
  o[0] = (unsigned int)f2bf(d.x) | ((unsigned int)f2bf(d.y) << 16);
  o[1] = (unsigned int)f2bf(d.z) | ((unsigned int)f2bf(d.w) << 16);
  *(u32x2*)(outp + i) = o;
}

// ---------------------------------------------------------------------------
// Generic bf16 GEMM: C[M,N] = A[M,K] @ B[N,K]^T, 128x128 tile, BK=64,
// 4 waves 2x2, each wave 64x64 via 4x4 MFMA 16x16x32 accs.
// EPI: 0 = plain bf16 store, 1 = f32 store Res + C*Scale[col], 2 = bf16 relu(C)^2
// ---------------------------------------------------------------------------
template <int EPI, typename OutT>
__global__ __launch_bounds__(256)
void gemm_bt(const ushort_t* __restrict__ A, const ushort_t* __restrict__ B,
             OutT* __restrict__ C, const float* __restrict__ Res,
             const float* __restrict__ Scale, int M, int N, int K) {
  __shared__ ushort_t As[128 * 64];
  __shared__ ushort_t Bs[128 * 64];
  const int tid = threadIdx.x;
  const int wave = tid >> 6, lane = tid & 63;
  const int quad = lane >> 4, l16 = lane & 15;
  const int bm = blockIdx.y * 128, bn = blockIdx.x * 128;
  const int wm = (wave >> 1) * 64, wn = (wave & 1) * 64;

  f32x4 acc[4][4] = {};

  const ushort_t* aBase = A + (size_t)bm * K;
  const ushort_t* bBase = B + (size_t)bn * K;
  for (int k0 = 0; k0 < K; k0 += 64) {
#pragma unroll
    for (int i = 0; i < 4; i++) {
      const int c = i * 256 + tid;
      const int r = c >> 3, cc = (c & 7) * 8;
      gld_lds16(aBase + (size_t)r * K + k0 + cc, &As[c * 8]);
      gld_lds16(bBase + (size_t)r * K + k0 + cc, &Bs[c * 8]);
    }
    __syncthreads();
#pragma unroll
    for (int ks = 0; ks < 2; ks++) {
      bf16x8 af[4], bfr[4];
#pragma unroll
      for (int t = 0; t < 4; t++) {
        af[t]  = *(const bf16x8*)&As[(wm + t * 16 + l16) * 64 + ks * 32 + quad * 8];
        bfr[t] = *(const bf16x8*)&Bs[(wn + t * 16 + l16) * 64 + ks * 32 + quad * 8];
      }
#pragma unroll
      for (int mt = 0; mt < 4; mt++)
#pragma unroll
        for (int nt = 0; nt < 4; nt++)
          acc[mt][nt] = __builtin_amdgcn_mfma_f32_16x16x32_bf16(af[mt], bfr[nt], acc[mt][nt], 0, 0, 0);
    }
    __syncthreads();
  }
  // epilogue: C/D layout col = lane&15, row = quad*4 + reg
#pragma unroll
  for (int mt = 0; mt < 4; mt++) {
#pragma unroll
    for (int r = 0; r < 4; r++) {
      const int row = bm + wm + mt * 16 + quad * 4 + r;
      const size_t base = (size_t)row * N;
#pragma unroll
      for (int nt = 0; nt < 4; nt++) {
        const int col = bn + wn + nt * 16 + l16;
        float v = acc[mt][nt][r];
        if (EPI == 1)      v = Res[base + col] + v * Scale[col];
        else if (EPI == 2) { v = fmaxf(v, 0.f); v = v * v; }
        if constexpr (sizeof(OutT) == 2) C[base + col] = f2bf(v);
        else                             C[base + col] = v;
      }
    }
  }
}

// ---------------------------------------------------------------------------
// Row RMSNorm over 2048 (f32 in, bf16 out), one block (256 thr) per row.
// ---------------------------------------------------------------------------
__global__ __launch_bounds__(256)
void rmsnorm_k(const float* __restrict__ X, ushort_t* __restrict__ Y) {
  const int row = blockIdx.x, tid = threadIdx.x;
  const float* x = X + (size_t)row * 2048 + tid * 8;
  float v[8];
  *(float4*)&v[0] = *(const float4*)x;
  *(float4*)&v[4] = *(const float4*)(x + 4);
  float ss = 0.f;
#pragma unroll
  for (int i = 0; i < 8; i++) ss += v[i] * v[i];
  for (int o = 32; o; o >>= 1) ss += __shfl_xor(ss, o, 64);
  __shared__ float red[4];
  if ((tid & 63) == 0) red[tid >> 6] = ss;
  __syncthreads();
  const float tot = red[0] + red[1] + red[2] + red[3];
  const float sc = rsqrtf(tot * (1.0f / 2048.0f) + 1e-6f);
  u32x4 o4;
#pragma unroll
  for (int i = 0; i < 4; i++)
    o4[i] = (unsigned int)f2bf(v[2 * i] * sc) | ((unsigned int)f2bf(v[2 * i + 1] * sc) << 16);
  *(u32x4*)(Y + (size_t)row * 2048 + tid * 8) = o4;
}

// ---------------------------------------------------------------------------
// QK-norm + rotary. One wave per (token, head). Lane l owns pair (l, l+64).
// q,k written back bf16 in-place into qkv buffer; k,v also written f32 to
// d_out sections.
// ---------------------------------------------------------------------------
__global__ __launch_bounds__(256)
void rotary_qk(ushort_t* __restrict__ qkv, float* __restrict__ kout,
               float* __restrict__ vout) {
  const int tid = threadIdx.x, wave = tid >> 6, lane = tid & 63;
  const int unit = blockIdx.x * 4 + wave;
  const int token = unit >> 4, h = unit & 15;
  const int t = token & 2047;
  ushort_t* qrow = qkv + (size_t)token * 6144 + h * 128;
  ushort_t* krow = qrow + 2048;
  const ushort_t* vrow = qrow + 4096;
  float q1 = bf2f(qrow[lane]), q2 = bf2f(qrow[lane + 64]);
  float k1 = bf2f(krow[lane]), k2 = bf2f(krow[lane + 64]);
  float sq = q1 * q1 + q2 * q2, sk = k1 * k1 + k2 * k2;
  for (int o = 32; o; o >>= 1) { sq += __shfl_xor(sq, o, 64); sk += __shfl_xor(sk, o, 64); }
  const float rq = rsqrtf(sq * (1.f / 128.f) + 1e-6f);
  const float rk = rsqrtf(sk * (1.f / 128.f) + 1e-6f);
  q1 *= rq; q2 *= rq; k1 *= rk; k2 *= rk;
  float c = 1.f, s = 0.f;
  if (lane < 32) {
    // f = 10000^(-lane/31); log2(10000)=13.28771237954945
    const float f = exp2f((float)lane * (-13.28771237954945f / 31.0f));
    const float th = (float)t * f;
    s = sinf(th); c = cosf(th);
  }
  const float qy1 = q1 * c + q2 * s, qy2 = -q1 * s + q2 * c;
  const float ky1 = k1 * c + k2 * s, ky2 = -k1 * s + k2 * c;
  const unsigned short qb1 = f2bf(qy1), qb2 = f2bf(qy2);
  const unsigned short kb1 = f2bf(ky1), kb2 = f2bf(ky2);
  qrow[lane] = qb1; qrow[lane + 64] = qb2;
  krow[lane] = kb1; krow[lane + 64] = kb2;
  float* ko = kout + (size_t)token * 2048 + h * 128;
  ko[lane] = bf2f(kb1); ko[lane + 64] = bf2f(kb2);
  float* vo = vout + (size_t)token * 2048 + h * 128;
  vo[lane] = bf2f(vrow[lane]); vo[lane + 64] = bf2f(vrow[lane + 64]);
}

// ---------------------------------------------------------------------------
// V transpose per (b,h): qkv v-section [T,128] -> Vt [128,T] (bf16) so flash
// PV B-operand reads are contiguous. 128x128 tile per block through padded LDS.
// ---------------------------------------------------------------------------
__global__ __launch_bounds__(256)
void transpose_v(const ushort_t* __restrict__ qkv, ushort_t* __restrict__ vt) {
  __shared__ ushort_t tile[128][136];
  const int t16 = blockIdx.x, h = blockIdx.y, b = blockIdx.z;
  const int tid = threadIdx.x;
#pragma unroll
  for (int i = 0; i < 8; i++) {
    const int c = i * 256 + tid;
    const int row = c >> 4, cc = (c & 15) * 8;
    const size_t tok = (size_t)(b * 2048 + t16 * 128 + row);
    u32x4 d = *(const u32x4*)(qkv + tok * 6144 + 4096 + h * 128 + cc);
    *(u32x4*)&tile[row][cc] = d;
  }
  __syncthreads();
#pragma unroll
  for (int i = 0; i < 8; i++) {
    const int c = i * 256 + tid;
    const int hr = c >> 4, tc = (c & 15) * 8;
    u32x4 o;
#pragma unroll
    for (int j = 0; j < 4; j++) {
      const unsigned int lo = tile[tc + 2 * j][hr];
      const unsigned int hi = tile[tc + 2 * j + 1][hr];
      o[j] = lo | (hi << 16);
    }
    *(u32x4*)(vt + ((size_t)(b * 16 + h) * 128 + hr) * 2048 + t16 * 128 + tc) = o;
  }
}

// ---------------------------------------------------------------------------
// Causal flash attention. Block = (qb,h,b): 128 q-rows, 4 waves x 32 rows.
// K-tile = 64 rows. Q frags in registers; K staged from qkv k-section
// [64][128]; V staged from pre-transposed Vt as [128 hd][64 k]; P through
// per-wave LDS (C->A layout).
// ---------------------------------------------------------------------------
__global__ __launch_bounds__(256)
void attn_k(const ushort_t* __restrict__ qkv, const ushort_t* __restrict__ vt,
            ushort_t* __restrict__ obuf) {
  __shared__ ushort_t kbuf[64 * 128];
  __shared__ ushort_t vbuf[128 * 64];
  __shared__ ushort_t pbuf[4][32 * 64];
  const int qb = blockIdx.x, h = blockIdx.y, b = blockIdx.z;
  const int tid = threadIdx.x, wave = tid >> 6, lane = tid & 63;
  const int quad = lane >> 4, l16 = lane & 15;
  const float SCALE = 0.08838834764831845f;  // 1/sqrt(128)

  bf16x8 qf[2][4];
#pragma unroll
  for (int mt = 0; mt < 2; mt++)
#pragma unroll
    for (int ks = 0; ks < 4; ks++) {
      const int tok = b * 2048 + qb * 128 + wave * 32 + mt * 16 + l16;
      qf[mt][ks] = *(const bf16x8*)(qkv + (size_t)tok * 6144 + h * 128 + ks * 32 + quad * 8);
    }
  f32x4 O[2][8] = {};
  float mrow[2][4], lrow[2][4];
#pragma unroll
  for (int mt = 0; mt < 2; mt++)
#pragma unroll
    for (int r = 0; r < 4; r++) { mrow[mt][r] = -__builtin_inff(); lrow[mt][r] = 0.f; }

  const int nkt = qb * 2 + 2;
  const size_t kb0 = (size_t)(b * 2048) * 6144 + 2048 + h * 128;  // k-section row base
  const size_t vt0 = (size_t)(b * 16 + h) * 128 * 2048;
  for (int kt = 0; kt < nkt; kt++) {
#pragma unroll
    for (int i = 0; i < 4; i++) {
      const int c = i * 256 + tid;
      const int kr = c >> 4, cc = (c & 15) * 8;
      gld_lds16(qkv + kb0 + (size_t)(kt * 64 + kr) * 6144 + cc, &kbuf[c * 8]);
      const int hr = c >> 3, vc = (c & 7) * 8;
      gld_lds16(vt + vt0 + (size_t)hr * 2048 + kt * 64 + vc, &vbuf[c * 8]);
    }
    __syncthreads();
    f32x4 S[2][4] = {};
#pragma unroll
    for (int ks = 0; ks < 4; ks++) {
      bf16x8 kf[4];
#pragma unroll
      for (int nt = 0; nt < 4; nt++)
        kf[nt] = *(const bf16x8*)&kbuf[(nt * 16 + l16) * 128 + ks * 32 + quad * 8];
#pragma unroll
      for (int mt = 0; mt < 2; mt++)
#pragma unroll
        for (int nt = 0; nt < 4; nt++)
          S[mt][nt] = __builtin_amdgcn_mfma_f32_16x16x32_bf16(qf[mt][ks], kf[nt], S[mt][nt], 0, 0, 0);
    }
    float alpha[2][4];
#pragma unroll
    for (int mt = 0; mt < 2; mt++) {
#pragma unroll
      for (int r = 0; r < 4; r++) {
        const int qr = qb * 128 + wave * 32 + mt * 16 + quad * 4 + r;
        float mx = -__builtin_inff();
#pragma unroll
        for (int nt = 0; nt < 4; nt++) {
          const int kc = kt * 64 + nt * 16 + l16;
          float sv = S[mt][nt][r] * SCALE;
          if (kc > qr) sv = -__builtin_inff();
          S[mt][nt][r] = sv;
          mx = fmaxf(mx, sv);
        }
        for (int o = 1; o < 16; o <<= 1) mx = fmaxf(mx, __shfl_xor(mx, o, 64));
        const float mnew = fmaxf(mrow[mt][r], mx);
        float rs = 0.f;
#pragma unroll
        for (int nt = 0; nt < 4; nt++) {
          const float p = exp2f((S[mt][nt][r] - mnew) * LOG2E);
          rs += p;
          pbuf[wave][(mt * 16 + quad * 4 + r) * 64 + nt * 16 + l16] = f2bf(p);
        }
        for (int o = 1; o < 16; o <<= 1) rs += __shfl_xor(rs, o, 64);
        const float a = exp2f((mrow[mt][r] - mnew) * LOG2E);
        alpha[mt][r] = a;
        lrow[mt][r] = lrow[mt][r] * a + rs;
        mrow[mt][r] = mnew;
      }
    }
#pragma unroll
    for (int mt = 0; mt < 2; mt++)
#pragma unroll
      for (int nto = 0; nto < 8; nto++)
#pragma unroll
        for (int r = 0; r < 4; r++)
          O[mt][nto][r] *= alpha[mt][r];
#pragma unroll
    for (int ks = 0; ks < 2; ks++) {
      bf16x8 pa[2];
#pragma unroll
      for (int mt = 0; mt < 2; mt++)
        pa[mt] = *(const bf16x8*)&pbuf[wave][(mt * 16 + l16) * 64 + ks * 32 + quad * 8];
#pragma unroll
      for (int nto = 0; nto < 8; nto++) {
        const bf16x8 vb = *(const bf16x8*)&vbuf[(nto * 16 + l16) * 64 + ks * 32 + quad * 8];
#pragma unroll
        for (int mt = 0; mt < 2; mt++)
          O[mt][nto] = __builtin_amdgcn_mfma_f32_16x16x32_bf16(pa[mt], vb, O[mt][nto], 0, 0, 0);
      }
    }
    __syncthreads();
  }
#pragma unroll
  for (int mt = 0; mt < 2; mt++)
#pragma unroll
    for (int r = 0; r < 4; r++) {
      const float inv = 1.0f / lrow[mt][r];
      const int row = b * 2048 + qb * 128 + wave * 32 + mt * 16 + quad * 4 + r;
      const size_t base = (size_t)row * 2048 + h * 128;
#pragma unroll
      for (int nto = 0; nto < 8; nto++)
        obuf[base + nto * 16 + l16] = f2bf(O[mt][nto][r] * inv);
    }
}

// ---------------------------------------------------------------------------
extern "C" void kernel_launch(void* const* d_in, const int* in_sizes, int n_in,
                              void* d_out, int out_size, void* d_ws, size_t ws_size,
                              hipStream_t stream) {
  (void)in_sizes; (void)n_in; (void)out_size; (void)ws_size;
  const float* x       = (const float*)d_in[0];
  const float* qkv_w   = (const float*)d_in[1];
  const float* o_w     = (const float*)d_in[2];
  const float* o_scale = (const float*)d_in[3];
  const float* w1      = (const float*)d_in[4];
  const float* w2      = (const float*)d_in[5];
  const float* mscale  = (const float*)d_in[6];
  float* outx = (float*)d_out;                       // [4,2048,2048]   = 16777216
  float* outk = outx + (size_t)16777216;             // [4,2048,16,128] = 16777216
  float* outv = outk + (size_t)16777216;             // [4,2048,16,128] = 16777216

  char* ws = (char*)d_ws;
  ushort_t* qkv    = (ushort_t*)(ws + 0);            // 96 MB  [8192,6144] bf16
  ushort_t* vt     = (ushort_t*)(ws + 100663296);    // 32 MB  [4,16,128,2048] bf16
  ushort_t* xn     = (ushort_t*)(ws + 134217728);    // 32 MB  bf16 (xn / o / xn2 serial reuse)
  float*    x1     = (float*)   (ws + 167772160);    // 64 MB  f32
  ushort_t* qkv_wb = (ushort_t*)(ws + 234881024);    // 24 MB  bf16
  ushort_t* o_wb   = (ushort_t*)(ws + 260046848);    //  8 MB
  ushort_t* w1b    = (ushort_t*)(ws + 268435456);    // 32 MB
  ushort_t* w2b    = (ushort_t*)(ws + 301989888);    // 32 MB  (total 320 MB)
  ushort_t* hbuf   = (ushort_t*)(ws + 0);            // 128 MB overlays qkv+vt (dead after attn)

  cvt_bf16<<<12288, 256, 0, stream>>>(qkv_w, qkv_wb, 12582912);
  cvt_bf16<<<4096,  256, 0, stream>>>(o_w,   o_wb,   4194304);
  cvt_bf16<<<16384, 256, 0, stream>>>(w1,    w1b,    16777216);
  cvt_bf16<<<16384, 256, 0, stream>>>(w2,    w2b,    16777216);

  rmsnorm_k<<<8192, 256, 0, stream>>>(x, xn);
  gemm_bt<0, ushort_t><<<dim3(48, 64), 256, 0, stream>>>(xn, qkv_wb, qkv, nullptr, nullptr, 8192, 6144, 2048);
  rotary_qk<<<32768, 256, 0, stream>>>(qkv, outk, outv);
  transpose_v<<<dim3(16, 16, 4), 256, 0, stream>>>(qkv, vt);
  attn_k<<<dim3(16, 16, 4), 256, 0, stream>>>(qkv, vt, xn /* o */);
  gemm_bt<1, float><<<dim3(16, 64), 256, 0, stream>>>(xn /* o */, o_wb, x1, x, o_scale, 8192, 2048, 2048);
  rmsnorm_k<<<8192, 256, 0, stream>>>(x1, xn);
  gemm_bt<2, ushort_t><<<dim3(64, 64), 256, 0, stream>>>(xn, w1b, hbuf, nullptr, nullptr, 8192, 8192, 2048);
  gemm_bt<1, float><<<dim3(16, 64), 256, 0, stream>>>(hbuf, w2b, outx, x1, mscale, 8192, 2048, 8192);
}